// Round 1
// baseline (980.222 us; speedup 1.0000x reference)
//
#include <hip/hip_runtime.h>
#include <hip/hip_bf16.h>

// Problem constants: B=4, T=1024, E=1024, ATT=64, NH=16, AH=1024.
// Rows of all GEMMs: M = B*T = 4096. K = N = 1024.

// C[M,N] = A[M,K] @ B[K,N] + bias[N]   (fp32, 64x64 block tile, 256 thr, 4x4/thr)
__global__ __launch_bounds__(256) void gemm_bias_kernel(
    const float* __restrict__ A, const float* __restrict__ B,
    const float* __restrict__ bias, float* __restrict__ C,
    int M, int N, int K)
{
    __shared__ float As[64][17];   // +1 pad breaks store conflicts
    __shared__ float Bs[16][64];

    const int tid = threadIdx.x;
    const int tx = tid & 15;       // 16 cols of 4
    const int ty = tid >> 4;       // 16 rows of 4
    const int m0 = blockIdx.y * 64;
    const int n0 = blockIdx.x * 64;

    const int arow = tid >> 2;          // 0..63
    const int ac4  = (tid & 3) * 4;     // 0,4,8,12
    const int brow = tid >> 4;          // 0..15
    const int bc4  = (tid & 15) * 4;    // 0..60

    float acc[4][4] = {};

    for (int k0 = 0; k0 < K; k0 += 16) {
        float4 av = *(const float4*)(A + (size_t)(m0 + arow) * K + k0 + ac4);
        As[arow][ac4 + 0] = av.x;
        As[arow][ac4 + 1] = av.y;
        As[arow][ac4 + 2] = av.z;
        As[arow][ac4 + 3] = av.w;
        float4 bv = *(const float4*)(B + (size_t)(k0 + brow) * N + n0 + bc4);
        *(float4*)(&Bs[brow][bc4]) = bv;
        __syncthreads();

        #pragma unroll
        for (int kk = 0; kk < 16; ++kk) {
            float a_[4];
            #pragma unroll
            for (int i = 0; i < 4; ++i) a_[i] = As[ty * 4 + i][kk];
            float4 b4 = *(const float4*)(&Bs[kk][tx * 4]);
            #pragma unroll
            for (int i = 0; i < 4; ++i) {
                acc[i][0] += a_[i] * b4.x;
                acc[i][1] += a_[i] * b4.y;
                acc[i][2] += a_[i] * b4.z;
                acc[i][3] += a_[i] * b4.w;
            }
        }
        __syncthreads();
    }

    float4 bb = *(const float4*)(bias + n0 + tx * 4);
    #pragma unroll
    for (int i = 0; i < 4; ++i) {
        float4 o;
        o.x = acc[i][0] + bb.x;
        o.y = acc[i][1] + bb.y;
        o.z = acc[i][2] + bb.z;
        o.w = acc[i][3] + bb.w;
        *(float4*)(C + (size_t)(m0 + ty * 4 + i) * N + n0 + tx * 4) = o;
    }
}

// Streaming-softmax attention.
// Heads: hd = a*4 + b (a in [0,64), b in [0,4)), head dim 16, seq 1024.
// Q/K/V stored [4096][1024] row-major: element (b*1024+t, a*16+h).
// One thread per query row; block = 256 rows; 4 blocks per head.
// Scores are bounded (|s| ~ 2), so exp without running-max is safe; softmax
// is exactly sum-normalized at the end (z = acc / l).
__global__ __launch_bounds__(256) void attn_kernel(
    const float* __restrict__ Q, const float* __restrict__ K,
    const float* __restrict__ V, float* __restrict__ Z)
{
    __shared__ float Ks[64][16];
    __shared__ float Vs[64][16];

    const int tid = threadIdx.x;
    const int hd = blockIdx.x >> 2;   // a*4+b
    const int qc = blockIdx.x & 3;
    const int a  = hd >> 2;
    const int b  = hd & 3;
    const int t  = qc * 256 + tid;
    const int col0 = a * 16;

    const size_t qoff = (size_t)(b * 1024 + t) * 1024 + col0;
    float4 q0 = *(const float4*)(Q + qoff + 0);
    float4 q1 = *(const float4*)(Q + qoff + 4);
    float4 q2 = *(const float4*)(Q + qoff + 8);
    float4 q3 = *(const float4*)(Q + qoff + 12);

    float l = 0.f;
    float4 acc0 = {0,0,0,0}, acc1 = {0,0,0,0}, acc2 = {0,0,0,0}, acc3 = {0,0,0,0};

    const int srow = tid >> 2;        // 0..63
    const int sc4  = (tid & 3) * 4;   // 0,4,8,12

    for (int j0 = 0; j0 < 1024; j0 += 64) {
        const size_t koff = (size_t)(b * 1024 + j0 + srow) * 1024 + col0 + sc4;
        *(float4*)(&Ks[srow][sc4]) = *(const float4*)(K + koff);
        *(float4*)(&Vs[srow][sc4]) = *(const float4*)(V + koff);
        __syncthreads();

        #pragma unroll 8
        for (int jj = 0; jj < 64; ++jj) {
            const float4* kr = (const float4*)(&Ks[jj][0]);
            float4 k0v = kr[0], k1v = kr[1], k2v = kr[2], k3v = kr[3];
            float s = q0.x * k0v.x + q0.y * k0v.y + q0.z * k0v.z + q0.w * k0v.w
                    + q1.x * k1v.x + q1.y * k1v.y + q1.z * k1v.z + q1.w * k1v.w
                    + q2.x * k2v.x + q2.y * k2v.y + q2.z * k2v.z + q2.w * k2v.w
                    + q3.x * k3v.x + q3.y * k3v.y + q3.z * k3v.z + q3.w * k3v.w;
            float p = __expf(s * 0.125f);   // scale = 1/sqrt(ATT) = 1/8
            l += p;
            const float4* vr = (const float4*)(&Vs[jj][0]);
            float4 v0 = vr[0], v1 = vr[1], v2 = vr[2], v3 = vr[3];
            acc0.x += p * v0.x; acc0.y += p * v0.y; acc0.z += p * v0.z; acc0.w += p * v0.w;
            acc1.x += p * v1.x; acc1.y += p * v1.y; acc1.z += p * v1.z; acc1.w += p * v1.w;
            acc2.x += p * v2.x; acc2.y += p * v2.y; acc2.z += p * v2.z; acc2.w += p * v2.w;
            acc3.x += p * v3.x; acc3.y += p * v3.y; acc3.z += p * v3.z; acc3.w += p * v3.w;
        }
        __syncthreads();
    }

    const float inv = 1.f / l;
    float* zp = Z + ((size_t)(hd * 1024 + t)) * 16;
    float4 o;
    o.x = acc0.x * inv; o.y = acc0.y * inv; o.z = acc0.z * inv; o.w = acc0.w * inv;
    *(float4*)(zp + 0) = o;
    o.x = acc1.x * inv; o.y = acc1.y * inv; o.z = acc1.z * inv; o.w = acc1.w * inv;
    *(float4*)(zp + 4) = o;
    o.x = acc2.x * inv; o.y = acc2.y * inv; o.z = acc2.z * inv; o.w = acc2.w * inv;
    *(float4*)(zp + 8) = o;
    o.x = acc3.x * inv; o.y = acc3.y * inv; o.z = acc3.z * inv; o.w = acc3.w * inv;
    *(float4*)(zp + 12) = o;
}

extern "C" void kernel_launch(void* const* d_in, const int* in_sizes, int n_in,
                              void* d_out, int out_size, void* d_ws, size_t ws_size,
                              hipStream_t stream) {
    const float* x  = (const float*)d_in[0];
    const float* Wq = (const float*)d_in[1];
    const float* bq = (const float*)d_in[2];
    const float* Wk = (const float*)d_in[3];
    const float* bk = (const float*)d_in[4];
    const float* Wv = (const float*)d_in[5];
    const float* bv = (const float*)d_in[6];
    const float* Wo = (const float*)d_in[7];
    const float* bo = (const float*)d_in[8];
    float* out = (float*)d_out;

    const int M = 4096, N = 1024, K = 1024;
    float* ws = (float*)d_ws;
    float* Q = ws;
    float* Kx = ws + (size_t)M * N;
    float* Vx = ws + (size_t)2 * M * N;
    float* Z  = ws + (size_t)3 * M * N;

    dim3 blk(256);
    dim3 grid(N / 64, M / 64);
    gemm_bias_kernel<<<grid, blk, 0, stream>>>(x, Wq, bq, Q, M, N, K);
    gemm_bias_kernel<<<grid, blk, 0, stream>>>(x, Wk, bk, Kx, M, N, K);
    gemm_bias_kernel<<<grid, blk, 0, stream>>>(x, Wv, bv, Vx, M, N, K);

    attn_kernel<<<dim3(1024), blk, 0, stream>>>(Q, Kx, Vx, Z);

    gemm_bias_kernel<<<grid, blk, 0, stream>>>(Z, Wo, bo, out, M, N, K);
}

// Round 2
// 472.383 us; speedup vs baseline: 2.0751x; 2.0751x over previous
//
#include <hip/hip_runtime.h>
#include <hip/hip_bf16.h>

// B=4, T=1024, E=1024, ATT=64, NH=16, AH=1024. M = B*T = 4096, K = N = 1024.
// Pipeline: cast x->bf16; transpose+cast W{q,k,v,o} -> [N][K] bf16;
//           3x MFMA GEMM (bf16 in, bf16 out Q/K/V); attn (fp32 compute, bf16 Z);
//           final MFMA GEMM (bf16 in, fp32 out).

typedef __bf16 bf16_t;
typedef bf16_t bf16x8 __attribute__((ext_vector_type(8)));
typedef float f32x4 __attribute__((ext_vector_type(4)));

// ---------- cast fp32 -> bf16, 8 elems/thread ----------
__global__ __launch_bounds__(256) void cast_f32_bf16(
    const float* __restrict__ in, bf16_t* __restrict__ out, int n8)
{
    int i = blockIdx.x * 256 + threadIdx.x;
    if (i >= n8) return;
    const float4* p = (const float4*)in + (size_t)i * 2;
    float4 a = p[0], b = p[1];
    bf16x8 o;
    o[0] = (bf16_t)a.x; o[1] = (bf16_t)a.y; o[2] = (bf16_t)a.z; o[3] = (bf16_t)a.w;
    o[4] = (bf16_t)b.x; o[5] = (bf16_t)b.y; o[6] = (bf16_t)b.z; o[7] = (bf16_t)b.w;
    *((bf16x8*)out + i) = o;
}

// ---------- transpose + cast: W [1024][1024] fp32 [K][N] -> [N][K] bf16 ----------
// grid (32, 32, 4): z selects matrix; out has 4 contiguous 1M-elem slabs.
__global__ __launch_bounds__(256) void transpose_cast(
    const float* __restrict__ W0, const float* __restrict__ W1,
    const float* __restrict__ W2, const float* __restrict__ W3,
    bf16_t* __restrict__ out)
{
    __shared__ float st[32][33];
    const float* W = (blockIdx.z == 0) ? W0 : (blockIdx.z == 1) ? W1
                   : (blockIdx.z == 2) ? W2 : W3;
    bf16_t* o = out + (size_t)blockIdx.z * 1024 * 1024;
    const int n0 = blockIdx.x * 32, k0 = blockIdx.y * 32;
    const int t = threadIdx.x;
    const int r = t >> 3, c4 = (t & 7) * 4;
    float4 v = *(const float4*)(W + (size_t)(k0 + r) * 1024 + n0 + c4);
    st[r][c4 + 0] = v.x; st[r][c4 + 1] = v.y; st[r][c4 + 2] = v.z; st[r][c4 + 3] = v.w;
    __syncthreads();
    bf16_t tmp[4] __attribute__((aligned(8)));
    #pragma unroll
    for (int i = 0; i < 4; ++i) tmp[i] = (bf16_t)st[c4 + i][r];
    *(uint2*)(o + (size_t)(n0 + r) * 1024 + k0 + c4) = *(const uint2*)tmp;
}

// ---------- bf16 MFMA GEMM: C[M,N] = A[M,K] @ Bt[N,K]^T + bias ----------
// Tile 128(M) x 64(N), BK=32, 256 threads (4 waves, 2x2 of 64x32 wave-tiles).
// Frag layouts (m89/m91-verified): A/B operand: free = lane&15, k = (lane>>4)*8+j;
// C/D: n = lane&15, m = (lane>>4)*4 + reg.
template<bool OUT_BF16>
__global__ __launch_bounds__(256) void gemm_bt(
    const bf16_t* __restrict__ A, const bf16_t* __restrict__ Bt,
    const float* __restrict__ bias, void* __restrict__ C,
    int M, int N, int K)
{
    __shared__ __align__(16) bf16_t As[128 * 40];  // 32 used + 8 pad (2-way alias = free)
    __shared__ __align__(16) bf16_t Bs[64 * 40];

    const int tid  = threadIdx.x;
    const int wave = tid >> 6;
    const int lane = tid & 63;
    const int quad = lane >> 4;
    const int l16  = lane & 15;
    const int m0 = blockIdx.y * 128;
    const int n0 = blockIdx.x * 64;
    const int wm = (wave >> 1) * 64;  // 0 or 64
    const int wn = (wave & 1) * 32;   // 0 or 32

    f32x4 acc[4][2] = {};

    const int srow = tid >> 2;        // 0..63
    const int skq  = (tid & 3) * 8;   // k elem offset: 0,8,16,24

    for (int k0 = 0; k0 < K; k0 += 32) {
        const bf16_t* ag = A + (size_t)(m0 + srow) * K + k0 + skq;
        *(uint4*)(&As[srow * 40 + skq])        = *(const uint4*)ag;
        *(uint4*)(&As[(srow + 64) * 40 + skq]) = *(const uint4*)(ag + (size_t)64 * K);
        const bf16_t* bg = Bt + (size_t)(n0 + srow) * K + k0 + skq;
        *(uint4*)(&Bs[srow * 40 + skq])        = *(const uint4*)bg;
        __syncthreads();

        bf16x8 af[4], bfr[2];
        #pragma unroll
        for (int mt = 0; mt < 4; ++mt)
            af[mt] = *(const bf16x8*)(&As[(wm + mt * 16 + l16) * 40 + quad * 8]);
        #pragma unroll
        for (int nt = 0; nt < 2; ++nt)
            bfr[nt] = *(const bf16x8*)(&Bs[(wn + nt * 16 + l16) * 40 + quad * 8]);
        #pragma unroll
        for (int mt = 0; mt < 4; ++mt)
            #pragma unroll
            for (int nt = 0; nt < 2; ++nt)
                acc[mt][nt] = __builtin_amdgcn_mfma_f32_16x16x32_bf16(
                    af[mt], bfr[nt], acc[mt][nt], 0, 0, 0);
        __syncthreads();
    }

    #pragma unroll
    for (int nt = 0; nt < 2; ++nt) {
        const int n = n0 + wn + nt * 16 + l16;
        const float bb = bias[n];
        #pragma unroll
        for (int mt = 0; mt < 4; ++mt) {
            #pragma unroll
            for (int i = 0; i < 4; ++i) {
                const int m = m0 + wm + mt * 16 + quad * 4 + i;
                const float val = acc[mt][nt][i] + bb;
                if (OUT_BF16) ((bf16_t*)C)[(size_t)m * N + n] = (bf16_t)val;
                else          ((float*)C)[(size_t)m * N + n]  = val;
            }
        }
    }
}

// ---------- attention: one block per head (hd = a*4+b), 4 queries/thread ----------
// Q/K/V bf16 [4096][1024]; row = b*1024+t, col = a*16+h. Scale = 1/sqrt(ATT) = 0.125.
// Scores bounded (~|2|) -> exp without running max is safe; exact sum-normalize at end.
__global__ __launch_bounds__(256) void attn_kernel(
    const bf16_t* __restrict__ Q, const bf16_t* __restrict__ K,
    const bf16_t* __restrict__ V, bf16_t* __restrict__ Z)
{
    __shared__ float Ks[64][16];
    __shared__ float Vs[64][16];

    const int tid = threadIdx.x;
    const int hd = blockIdx.x;
    const int a = hd >> 2, b = hd & 3;
    const int col0 = a * 16;

    float q[4][16];
    #pragma unroll
    for (int i = 0; i < 4; ++i) {
        const bf16x8* qp = (const bf16x8*)(Q + ((size_t)(b * 1024 + tid + 256 * i) * 1024 + col0));
        bf16x8 q0 = qp[0], q1 = qp[1];
        #pragma unroll
        for (int j = 0; j < 8; ++j) { q[i][j] = (float)q0[j]; q[i][8 + j] = (float)q1[j]; }
    }

    float l[4] = {0.f, 0.f, 0.f, 0.f};
    float acc[4][16] = {};

    const int mat = tid >> 7;        // 0: K tile, 1: V tile
    const int rr  = (tid >> 1) & 63;
    const int hh  = tid & 1;

    for (int j0 = 0; j0 < 1024; j0 += 64) {
        const bf16_t* src = (mat ? V : K)
            + ((size_t)(b * 1024 + j0 + rr) * 1024 + col0 + hh * 8);
        bf16x8 kv = *(const bf16x8*)src;
        float* dst = mat ? &Vs[rr][hh * 8] : &Ks[rr][hh * 8];
        float4 lo, hi;
        lo.x = (float)kv[0]; lo.y = (float)kv[1]; lo.z = (float)kv[2]; lo.w = (float)kv[3];
        hi.x = (float)kv[4]; hi.y = (float)kv[5]; hi.z = (float)kv[6]; hi.w = (float)kv[7];
        *(float4*)dst = lo; *(float4*)(dst + 4) = hi;
        __syncthreads();

        #pragma unroll 4
        for (int jj = 0; jj < 64; ++jj) {
            float kk[16], vv[16];
            *(float4*)&kk[0]  = *(const float4*)&Ks[jj][0];
            *(float4*)&kk[4]  = *(const float4*)&Ks[jj][4];
            *(float4*)&kk[8]  = *(const float4*)&Ks[jj][8];
            *(float4*)&kk[12] = *(const float4*)&Ks[jj][12];
            float s[4] = {0.f, 0.f, 0.f, 0.f};
            #pragma unroll
            for (int h = 0; h < 16; ++h) {
                const float kv_ = kk[h];
                #pragma unroll
                for (int i = 0; i < 4; ++i) s[i] = fmaf(q[i][h], kv_, s[i]);
            }
            float p[4];
            #pragma unroll
            for (int i = 0; i < 4; ++i) { p[i] = __expf(s[i] * 0.125f); l[i] += p[i]; }
            *(float4*)&vv[0]  = *(const float4*)&Vs[jj][0];
            *(float4*)&vv[4]  = *(const float4*)&Vs[jj][4];
            *(float4*)&vv[8]  = *(const float4*)&Vs[jj][8];
            *(float4*)&vv[12] = *(const float4*)&Vs[jj][12];
            #pragma unroll
            for (int h = 0; h < 16; ++h) {
                const float v_ = vv[h];
                #pragma unroll
                for (int i = 0; i < 4; ++i) acc[i][h] = fmaf(p[i], v_, acc[i][h]);
            }
        }
        __syncthreads();
    }

    #pragma unroll
    for (int i = 0; i < 4; ++i) {
        const float inv = 1.f / l[i];
        bf16x8 o0, o1;
        #pragma unroll
        for (int j = 0; j < 8; ++j) {
            o0[j] = (bf16_t)(acc[i][j] * inv);
            o1[j] = (bf16_t)(acc[i][8 + j] * inv);
        }
        bf16x8* zp = (bf16x8*)(Z + ((size_t)(hd * 1024 + tid + 256 * i) * 16));
        zp[0] = o0; zp[1] = o1;
    }
}

extern "C" void kernel_launch(void* const* d_in, const int* in_sizes, int n_in,
                              void* d_out, int out_size, void* d_ws, size_t ws_size,
                              hipStream_t stream) {
    const float* x  = (const float*)d_in[0];
    const float* Wq = (const float*)d_in[1];
    const float* bq = (const float*)d_in[2];
    const float* Wk = (const float*)d_in[3];
    const float* bk = (const float*)d_in[4];
    const float* Wv = (const float*)d_in[5];
    const float* bv = (const float*)d_in[6];
    const float* Wo = (const float*)d_in[7];
    const float* bo = (const float*)d_in[8];
    float* out = (float*)d_out;

    const int M = 4096, N = 1024, K = 1024;

    // ws layout (bytes): x_bf 8MB | Wt 4x2MB | Q 8MB | K 8MB | V 8MB | Z 8MB = 48MB
    char* ws = (char*)d_ws;
    bf16_t* x_bf = (bf16_t*)(ws);
    bf16_t* Wt   = (bf16_t*)(ws + (8u << 20));           // 4 slabs: q,k,v,o
    bf16_t* Qb   = (bf16_t*)(ws + (16u << 20));
    bf16_t* Kb   = (bf16_t*)(ws + (24u << 20));
    bf16_t* Vb   = (bf16_t*)(ws + (32u << 20));
    bf16_t* Zb   = (bf16_t*)(ws + (40u << 20));
    bf16_t* WtQ = Wt;
    bf16_t* WtK = Wt + (size_t)1 * 1024 * 1024;
    bf16_t* WtV = Wt + (size_t)2 * 1024 * 1024;
    bf16_t* WtO = Wt + (size_t)3 * 1024 * 1024;

    cast_f32_bf16<<<dim3(2048), dim3(256), 0, stream>>>(x, x_bf, 524288);
    transpose_cast<<<dim3(32, 32, 4), dim3(256), 0, stream>>>(Wq, Wk, Wv, Wo, Wt);

    dim3 gblk(256);
    dim3 ggrid(N / 64, M / 128);   // (16, 32) = 512 blocks
    gemm_bt<true><<<ggrid, gblk, 0, stream>>>(x_bf, WtQ, bq, (void*)Qb, M, N, K);
    gemm_bt<true><<<ggrid, gblk, 0, stream>>>(x_bf, WtK, bk, (void*)Kb, M, N, K);
    gemm_bt<true><<<ggrid, gblk, 0, stream>>>(x_bf, WtV, bv, (void*)Vb, M, N, K);

    attn_kernel<<<dim3(256), dim3(256), 0, stream>>>(Qb, Kb, Vb, Zb);

    gemm_bt<false><<<ggrid, gblk, 0, stream>>>(Zb, WtO, bo, (void*)out, M, N, K);
}

// Round 3
// 271.495 us; speedup vs baseline: 3.6105x; 1.7399x over previous
//
#include <hip/hip_runtime.h>
#include <hip/hip_bf16.h>

// B=4, T=1024, E=1024, ATT=64, NH=16, AH=1024. M = B*T = 4096, K = N = 1024.
// Pipeline: cast x->bf16; transpose+cast W{q,k,v,o} -> [N][K] bf16;
//           3x MFMA GEMM (bf16 out Q/K/V); MFMA flash attention (bf16 Z);
//           final MFMA GEMM (fp32 out).

typedef __bf16 bf16_t;
typedef bf16_t bf16x8 __attribute__((ext_vector_type(8)));
typedef float f32x4 __attribute__((ext_vector_type(4)));

// ---------- cast fp32 -> bf16, 8 elems/thread ----------
__global__ __launch_bounds__(256) void cast_f32_bf16(
    const float* __restrict__ in, bf16_t* __restrict__ out, int n8)
{
    int i = blockIdx.x * 256 + threadIdx.x;
    if (i >= n8) return;
    const float4* p = (const float4*)in + (size_t)i * 2;
    float4 a = p[0], b = p[1];
    bf16x8 o;
    o[0] = (bf16_t)a.x; o[1] = (bf16_t)a.y; o[2] = (bf16_t)a.z; o[3] = (bf16_t)a.w;
    o[4] = (bf16_t)b.x; o[5] = (bf16_t)b.y; o[6] = (bf16_t)b.z; o[7] = (bf16_t)b.w;
    *((bf16x8*)out + i) = o;
}

// ---------- transpose + cast: W [1024][1024] fp32 [K][N] -> [N][K] bf16 ----------
__global__ __launch_bounds__(256) void transpose_cast(
    const float* __restrict__ W0, const float* __restrict__ W1,
    const float* __restrict__ W2, const float* __restrict__ W3,
    bf16_t* __restrict__ out)
{
    __shared__ float st[32][33];
    const float* W = (blockIdx.z == 0) ? W0 : (blockIdx.z == 1) ? W1
                   : (blockIdx.z == 2) ? W2 : W3;
    bf16_t* o = out + (size_t)blockIdx.z * 1024 * 1024;
    const int n0 = blockIdx.x * 32, k0 = blockIdx.y * 32;
    const int t = threadIdx.x;
    const int r = t >> 3, c4 = (t & 7) * 4;
    float4 v = *(const float4*)(W + (size_t)(k0 + r) * 1024 + n0 + c4);
    st[r][c4 + 0] = v.x; st[r][c4 + 1] = v.y; st[r][c4 + 2] = v.z; st[r][c4 + 3] = v.w;
    __syncthreads();
    bf16_t tmp[4] __attribute__((aligned(8)));
    #pragma unroll
    for (int i = 0; i < 4; ++i) tmp[i] = (bf16_t)st[c4 + i][r];
    *(uint2*)(o + (size_t)(n0 + r) * 1024 + k0 + c4) = *(const uint2*)tmp;
}

// ---------- bf16 MFMA GEMM: C[M,N] = A[M,K] @ Bt[N,K]^T + bias ----------
template<bool OUT_BF16>
__global__ __launch_bounds__(256) void gemm_bt(
    const bf16_t* __restrict__ A, const bf16_t* __restrict__ Bt,
    const float* __restrict__ bias, void* __restrict__ C,
    int M, int N, int K)
{
    __shared__ __align__(16) bf16_t As[128 * 40];
    __shared__ __align__(16) bf16_t Bs[64 * 40];

    const int tid  = threadIdx.x;
    const int wave = tid >> 6;
    const int lane = tid & 63;
    const int quad = lane >> 4;
    const int l16  = lane & 15;
    const int m0 = blockIdx.y * 128;
    const int n0 = blockIdx.x * 64;
    const int wm = (wave >> 1) * 64;
    const int wn = (wave & 1) * 32;

    f32x4 acc[4][2] = {};

    const int srow = tid >> 2;
    const int skq  = (tid & 3) * 8;

    for (int k0 = 0; k0 < K; k0 += 32) {
        const bf16_t* ag = A + (size_t)(m0 + srow) * K + k0 + skq;
        *(uint4*)(&As[srow * 40 + skq])        = *(const uint4*)ag;
        *(uint4*)(&As[(srow + 64) * 40 + skq]) = *(const uint4*)(ag + (size_t)64 * K);
        const bf16_t* bg = Bt + (size_t)(n0 + srow) * K + k0 + skq;
        *(uint4*)(&Bs[srow * 40 + skq])        = *(const uint4*)bg;
        __syncthreads();

        bf16x8 af[4], bfr[2];
        #pragma unroll
        for (int mt = 0; mt < 4; ++mt)
            af[mt] = *(const bf16x8*)(&As[(wm + mt * 16 + l16) * 40 + quad * 8]);
        #pragma unroll
        for (int nt = 0; nt < 2; ++nt)
            bfr[nt] = *(const bf16x8*)(&Bs[(wn + nt * 16 + l16) * 40 + quad * 8]);
        #pragma unroll
        for (int mt = 0; mt < 4; ++mt)
            #pragma unroll
            for (int nt = 0; nt < 2; ++nt)
                acc[mt][nt] = __builtin_amdgcn_mfma_f32_16x16x32_bf16(
                    af[mt], bfr[nt], acc[mt][nt], 0, 0, 0);
        __syncthreads();
    }

    #pragma unroll
    for (int nt = 0; nt < 2; ++nt) {
        const int n = n0 + wn + nt * 16 + l16;
        const float bb = bias[n];
        #pragma unroll
        for (int mt = 0; mt < 4; ++mt) {
            #pragma unroll
            for (int i = 0; i < 4; ++i) {
                const int m = m0 + wm + mt * 16 + quad * 4 + i;
                const float val = acc[mt][nt][i] + bb;
                if (OUT_BF16) ((bf16_t*)C)[(size_t)m * N + n] = (bf16_t)val;
                else          ((float*)C)[(size_t)m * N + n]  = val;
            }
        }
    }
}

// ---------- MFMA flash attention ----------
// Grid 1024: block = (head hd = bx>>2, q-chunk qc = bx&3). 256 thr = 4 waves,
// wave handles 64 q rows. Per 64-key tile: S = Q K^T via mfma (d=16 zero-padded
// to K=32), p = exp2(s*0.125*log2e), P round-trips LDS in a key-PERMUTED order
// (kappa = l16*4+nt) so both P writes (b64) and PV fragment reads (b128) are
// vectorized; V is staged transposed with identically permuted columns (sums
// over keys are order-agnostic). No running max needed: |s*scale| <~ 2.
// l = sum p accumulated per lane (C-layout rows), cross-lane reduced at end;
// z = zacc / l. Strides padded to 72 elems (144 B): 16B-aligned b128 + uniform
// bank spread.
__global__ __launch_bounds__(256, 4) void attn_kernel(
    const bf16_t* __restrict__ Q, const bf16_t* __restrict__ K,
    const bf16_t* __restrict__ V, bf16_t* __restrict__ Z)
{
    __shared__ __align__(16) bf16_t Pw[4][64 * 72];   // per-wave P tile [64 q][64 kappa]
    __shared__ __align__(16) bf16_t Vt[16 * 72];      // [16 d][64 kappa], shared

    const int tid  = threadIdx.x;
    const int wave = tid >> 6;
    const int lane = tid & 63;
    const int quad = lane >> 4;
    const int l16  = lane & 15;
    const int hd = blockIdx.x >> 2;
    const int qc = blockIdx.x & 3;
    const int a = hd >> 2, b = hd & 3;
    const int col0 = a * 16;
    const int qbase = qc * 256 + wave * 64;

    const float SC = 0.125f * 1.44269504088896340736f;  // scale * log2(e)

    // Q A-fragments: A[m=l16][k=quad*8+j], k=d in [0,16) -> quads 2,3 zero.
    bf16x8 qf[4] = {};
    if (quad < 2) {
        #pragma unroll
        for (int mt = 0; mt < 4; ++mt)
            qf[mt] = *(const bf16x8*)(Q +
                (size_t)(b * 1024 + qbase + mt * 16 + l16) * 1024 + col0 + quad * 8);
    }

    f32x4 zacc[4] = {};
    f32x4 lsum[4] = {};
    bf16_t* myP = &Pw[wave][0];

    for (int j0 = 0; j0 < 1024; j0 += 64) {
        __syncthreads();   // all waves done reading previous Vt
        // ---- stage Vt with permuted columns: kappa(r) = (r&15)*4 + (r>>4) ----
        {
            const int r  = tid >> 2;          // key row 0..63
            const int dq = (tid & 3) * 4;     // d cols 0,4,8,12
            uint2 vv = *(const uint2*)(V +
                (size_t)(b * 1024 + j0 + r) * 1024 + col0 + dq);
            bf16_t t4[4] __attribute__((aligned(8)));
            *(uint2*)t4 = vv;
            const int kcol = (r & 15) * 4 + (r >> 4);
            #pragma unroll
            for (int ii = 0; ii < 4; ++ii)
                Vt[(dq + ii) * 72 + kcol] = t4[ii];
        }
        // ---- K B-fragments (direct global, quads 2,3 zero) ----
        bf16x8 kf[4] = {};
        if (quad < 2) {
            #pragma unroll
            for (int nt = 0; nt < 4; ++nt)
                kf[nt] = *(const bf16x8*)(K +
                    (size_t)(b * 1024 + j0 + nt * 16 + l16) * 1024 + col0 + quad * 8);
        }
        __syncthreads();   // Vt staged

        // ---- S = Q K^T, exp, pack to P (permuted key order) ----
        #pragma unroll
        for (int mt = 0; mt < 4; ++mt) {
            f32x4 s[4];
            #pragma unroll
            for (int nt = 0; nt < 4; ++nt) {
                f32x4 zc = {0.f, 0.f, 0.f, 0.f};
                s[nt] = __builtin_amdgcn_mfma_f32_16x16x32_bf16(qf[mt], kf[nt], zc, 0, 0, 0);
            }
            #pragma unroll
            for (int i = 0; i < 4; ++i) {
                bf16_t pk4[4] __attribute__((aligned(8)));
                #pragma unroll
                for (int nt = 0; nt < 4; ++nt) {
                    float p = exp2f(s[nt][i] * SC);
                    lsum[mt][i] += p;
                    pk4[nt] = (bf16_t)p;
                }
                // row q = mt*16 + quad*4 + i, cols kappa = l16*4 .. +3
                *(uint2*)(myP + (mt * 16 + quad * 4 + i) * 72 + l16 * 4) = *(const uint2*)pk4;
            }
        }

        // ---- Z += P V  (A = P [q][kappa], B = Vt [d][kappa]) ----
        #pragma unroll
        for (int kt = 0; kt < 2; ++kt) {
            bf16x8 vf = *(const bf16x8*)(&Vt[l16 * 72 + kt * 32 + quad * 8]);
            #pragma unroll
            for (int mt = 0; mt < 4; ++mt) {
                bf16x8 pf = *(const bf16x8*)(myP + (mt * 16 + l16) * 72 + kt * 32 + quad * 8);
                zacc[mt] = __builtin_amdgcn_mfma_f32_16x16x32_bf16(pf, vf, zacc[mt], 0, 0, 0);
            }
        }
    }

    // ---- epilogue: reduce l across the 16 key-column lanes, normalize, store ----
    #pragma unroll
    for (int mt = 0; mt < 4; ++mt) {
        #pragma unroll
        for (int i = 0; i < 4; ++i) {
            float l = lsum[mt][i];
            l += __shfl_xor(l, 1);
            l += __shfl_xor(l, 2);
            l += __shfl_xor(l, 4);
            l += __shfl_xor(l, 8);
            const float inv = 1.0f / l;
            const int t = qbase + mt * 16 + quad * 4 + i;
            Z[((size_t)hd * 1024 + t) * 16 + l16] = (bf16_t)(zacc[mt][i] * inv);
        }
    }
}

extern "C" void kernel_launch(void* const* d_in, const int* in_sizes, int n_in,
                              void* d_out, int out_size, void* d_ws, size_t ws_size,
                              hipStream_t stream) {
    const float* x  = (const float*)d_in[0];
    const float* Wq = (const float*)d_in[1];
    const float* bq = (const float*)d_in[2];
    const float* Wk = (const float*)d_in[3];
    const float* bk = (const float*)d_in[4];
    const float* Wv = (const float*)d_in[5];
    const float* bv = (const float*)d_in[6];
    const float* Wo = (const float*)d_in[7];
    const float* bo = (const float*)d_in[8];
    float* out = (float*)d_out;

    const int M = 4096, N = 1024, K = 1024;

    char* ws = (char*)d_ws;
    bf16_t* x_bf = (bf16_t*)(ws);
    bf16_t* Wt   = (bf16_t*)(ws + (8u << 20));
    bf16_t* Qb   = (bf16_t*)(ws + (16u << 20));
    bf16_t* Kb   = (bf16_t*)(ws + (24u << 20));
    bf16_t* Vb   = (bf16_t*)(ws + (32u << 20));
    bf16_t* Zb   = (bf16_t*)(ws + (40u << 20));
    bf16_t* WtQ = Wt;
    bf16_t* WtK = Wt + (size_t)1 * 1024 * 1024;
    bf16_t* WtV = Wt + (size_t)2 * 1024 * 1024;
    bf16_t* WtO = Wt + (size_t)3 * 1024 * 1024;

    cast_f32_bf16<<<dim3(2048), dim3(256), 0, stream>>>(x, x_bf, 524288);
    transpose_cast<<<dim3(32, 32, 4), dim3(256), 0, stream>>>(Wq, Wk, Wv, Wo, Wt);

    dim3 gblk(256);
    dim3 ggrid(N / 64, M / 128);
    gemm_bt<true><<<ggrid, gblk, 0, stream>>>(x_bf, WtQ, bq, (void*)Qb, M, N, K);
    gemm_bt<true><<<ggrid, gblk, 0, stream>>>(x_bf, WtK, bk, (void*)Kb, M, N, K);
    gemm_bt<true><<<ggrid, gblk, 0, stream>>>(x_bf, WtV, bv, (void*)Vb, M, N, K);

    attn_kernel<<<dim3(1024), dim3(256), 0, stream>>>(Qb, Kb, Vb, Zb);

    gemm_bt<false><<<ggrid, gblk, 0, stream>>>(Zb, WtO, bo, (void*)out, M, N, K);
}

// Round 4
// 221.699 us; speedup vs baseline: 4.4214x; 1.2246x over previous
//
#include <hip/hip_runtime.h>
#include <hip/hip_bf16.h>

// B=4, T=1024, E=1024, ATT=64, NH=16, AH=1024. M = B*T = 4096, K = N = 1024.
// Pipeline: cast x->bf16; transpose+cast W{q,k,v,o} -> [N][K] bf16;
//           ONE fused QKV MFMA GEMM (m97-style global_load_lds, K-slab
//           pre-scaled by 0.125*log2e); MFMA flash attention (l via ones-MFMA);
//           O-projection GEMM (fp32 out).

typedef __bf16 bf16_t;
typedef bf16_t bf16x8 __attribute__((ext_vector_type(8)));
typedef float f32x4 __attribute__((ext_vector_type(4)));

#define SCALE_LOG2E 0.18033688011112042f  /* 0.125 * log2(e) */

__device__ __forceinline__ void async16(const bf16_t* g, void* l) {
    __builtin_amdgcn_global_load_lds(
        (const __attribute__((address_space(1))) unsigned int*)g,
        (__attribute__((address_space(3))) unsigned int*)l,
        16, 0, 0);
}

// ---------- cast fp32 -> bf16, 8 elems/thread ----------
__global__ __launch_bounds__(256) void cast_f32_bf16(
    const float* __restrict__ in, bf16_t* __restrict__ out, int n8)
{
    int i = blockIdx.x * 256 + threadIdx.x;
    if (i >= n8) return;
    const float4* p = (const float4*)in + (size_t)i * 2;
    float4 a = p[0], b = p[1];
    bf16x8 o;
    o[0] = (bf16_t)a.x; o[1] = (bf16_t)a.y; o[2] = (bf16_t)a.z; o[3] = (bf16_t)a.w;
    o[4] = (bf16_t)b.x; o[5] = (bf16_t)b.y; o[6] = (bf16_t)b.z; o[7] = (bf16_t)b.w;
    *((bf16x8*)out + i) = o;
}

// ---------- transpose + cast: W [1024][1024] fp32 [K][N] -> [N][K] bf16 ----------
__global__ __launch_bounds__(256) void transpose_cast(
    const float* __restrict__ W0, const float* __restrict__ W1,
    const float* __restrict__ W2, const float* __restrict__ W3,
    bf16_t* __restrict__ out)
{
    __shared__ float st[32][33];
    const float* W = (blockIdx.z == 0) ? W0 : (blockIdx.z == 1) ? W1
                   : (blockIdx.z == 2) ? W2 : W3;
    bf16_t* o = out + (size_t)blockIdx.z * 1024 * 1024;
    const int n0 = blockIdx.x * 32, k0 = blockIdx.y * 32;
    const int t = threadIdx.x;
    const int r = t >> 3, c4 = (t & 7) * 4;
    float4 v = *(const float4*)(W + (size_t)(k0 + r) * 1024 + n0 + c4);
    st[r][c4 + 0] = v.x; st[r][c4 + 1] = v.y; st[r][c4 + 2] = v.z; st[r][c4 + 3] = v.w;
    __syncthreads();
    bf16_t tmp[4] __attribute__((aligned(8)));
    #pragma unroll
    for (int i = 0; i < 4; ++i) tmp[i] = (bf16_t)st[c4 + i][r];
    *(uint2*)(o + (size_t)(n0 + r) * 1024 + k0 + c4) = *(const uint2*)tmp;
}

// ---------- m97-style MFMA GEMM: C = A[M,1024] @ Bt[N,1024]^T + bias ----------
// Tile 128x128, BK=32, 256 thr = 4 waves in 2x2, each wave 64x64 (acc 4x4).
// Staging via global_load_lds width-16 (4 calls/stage). LDS unpadded
// [row][32] bf16 (64 B/row); XOR swizzle chunk^=(row>>1)&3 applied on the
// GLOBAL address (LDS dst is wave-uniform base + lane*16, can't swizzle) ->
// frag ds_read_b128 is 2-way bank-aliased = free.
// FUSED: Bt=[3072][1024] (Wq|Wk|Wv slabs), epilogue routes slab n0>>10 to
// Qo/Ko/Vo bf16 with per-slab bias; K-slab scaled by SCALE_LOG2E.
// else: fp32 out Fo with bias b0.
template<bool FUSED>
__global__ __launch_bounds__(256, 3) void gemm_glds(
    const bf16_t* __restrict__ A, const bf16_t* __restrict__ Bt,
    const float* __restrict__ b0, const float* __restrict__ b1,
    const float* __restrict__ b2,
    bf16_t* __restrict__ Qo, bf16_t* __restrict__ Ko, bf16_t* __restrict__ Vo,
    float* __restrict__ Fo)
{
    const int K = 1024;
    __shared__ __align__(16) bf16_t As[128 * 32];
    __shared__ __align__(16) bf16_t Bs[128 * 32];

    const int tid  = threadIdx.x;
    const int wave = tid >> 6;
    const int lane = tid & 63;
    const int quad = lane >> 4;
    const int l16  = lane & 15;
    const int m0 = blockIdx.y * 128;
    const int n0 = blockIdx.x * 128;
    const int wm = (wave >> 1) * 64;
    const int wn = (wave & 1) * 64;

    // staging: slot s = j*256+tid; row = s>>2, store-chunk = tid&3,
    // logical chunk = (tid&3) ^ ((row>>1)&3)  (8 bf16 per chunk)
    int goffA[2], goffB[2];
    #pragma unroll
    for (int j = 0; j < 2; ++j) {
        const int row = j * 64 + (tid >> 2);
        const int cl  = (tid & 3) ^ ((row >> 1) & 3);
        goffA[j] = (m0 + row) * K + cl * 8;
        goffB[j] = (n0 + row) * K + cl * 8;
    }
    const int ldsoff = wave * 1024;   // bytes within each j-half (4096 B)

    f32x4 acc[4][4] = {};
    const int sw = (l16 >> 1) & 3;

    for (int k0 = 0; k0 < K; k0 += 32) {
        #pragma unroll
        for (int j = 0; j < 2; ++j) {
            async16(A + goffA[j] + k0, (char*)As + j * 4096 + ldsoff);
            async16(Bt + goffB[j] + k0, (char*)Bs + j * 4096 + ldsoff);
        }
        __syncthreads();

        bf16x8 af[4], bfr[4];
        #pragma unroll
        for (int mt = 0; mt < 4; ++mt)
            af[mt] = *(const bf16x8*)(&As[(wm + mt * 16 + l16) * 32 + (quad ^ sw) * 8]);
        #pragma unroll
        for (int nt = 0; nt < 4; ++nt)
            bfr[nt] = *(const bf16x8*)(&Bs[(wn + nt * 16 + l16) * 32 + (quad ^ sw) * 8]);
        #pragma unroll
        for (int mt = 0; mt < 4; ++mt)
            #pragma unroll
            for (int nt = 0; nt < 4; ++nt)
                acc[mt][nt] = __builtin_amdgcn_mfma_f32_16x16x32_bf16(
                    af[mt], bfr[nt], acc[mt][nt], 0, 0, 0);
        __syncthreads();
    }

    if (FUSED) {
        const int sel = n0 >> 10;
        const float* bias = (sel == 0) ? b0 : (sel == 1) ? b1 : b2;
        bf16_t* Cout      = (sel == 0) ? Qo : (sel == 1) ? Ko : Vo;
        const float scl   = (sel == 1) ? SCALE_LOG2E : 1.0f;
        const int nb = n0 & 1023;
        #pragma unroll
        for (int nt = 0; nt < 4; ++nt) {
            const int n = nb + wn + nt * 16 + l16;
            const float bb = bias[n];
            #pragma unroll
            for (int mt = 0; mt < 4; ++mt)
                #pragma unroll
                for (int i = 0; i < 4; ++i) {
                    const int m = m0 + wm + mt * 16 + quad * 4 + i;
                    Cout[(size_t)m * 1024 + n] = (bf16_t)((acc[mt][nt][i] + bb) * scl);
                }
        }
    } else {
        #pragma unroll
        for (int nt = 0; nt < 4; ++nt) {
            const int n = n0 + wn + nt * 16 + l16;
            const float bb = b0[n];
            #pragma unroll
            for (int mt = 0; mt < 4; ++mt)
                #pragma unroll
                for (int i = 0; i < 4; ++i) {
                    const int m = m0 + wm + mt * 16 + quad * 4 + i;
                    Fo[(size_t)m * 1024 + n] = acc[mt][nt][i] + bb;
                }
        }
    }
}

// ---------- MFMA flash attention ----------
// Grid 1024: (head hd = bx>>2, q-chunk qc = bx&3). 256 thr = 4 waves, wave
// handles 64 q rows. K input is PRE-SCALED by 0.125*log2e (QKV epilogue), so
// p = exp2(s) directly. l = sum_k p computed via extra MFMA with all-ones B
// (idle MFMA pipe) -> no per-score VALU add, no epilogue shuffle.
// P round-trips LDS key-permuted (kappa = l16*4+nt; V staged with same
// permutation -> sums over keys unchanged). No running max: |s| bounded.
__global__ __launch_bounds__(256, 4) void attn_kernel(
    const bf16_t* __restrict__ Q, const bf16_t* __restrict__ K,
    const bf16_t* __restrict__ V, bf16_t* __restrict__ Z)
{
    __shared__ __align__(16) bf16_t Pw[4][64 * 72];   // per-wave P [64 q][64 kappa]
    __shared__ __align__(16) bf16_t Vt[16 * 72];      // [16 d][64 kappa]

    const int tid  = threadIdx.x;
    const int wave = tid >> 6;
    const int lane = tid & 63;
    const int quad = lane >> 4;
    const int l16  = lane & 15;
    const int hd = blockIdx.x >> 2;
    const int qc = blockIdx.x & 3;
    const int a = hd >> 2, b = hd & 3;
    const int col0 = a * 16;
    const int qbase = qc * 256 + wave * 64;

    bf16x8 qf[4] = {};
    if (quad < 2) {
        #pragma unroll
        for (int mt = 0; mt < 4; ++mt)
            qf[mt] = *(const bf16x8*)(Q +
                (size_t)(b * 1024 + qbase + mt * 16 + l16) * 1024 + col0 + quad * 8);
    }

    bf16x8 ones;
    #pragma unroll
    for (int j = 0; j < 8; ++j) ones[j] = (bf16_t)1.0f;

    f32x4 zacc[4] = {};
    f32x4 lacc[4] = {};
    bf16_t* myP = &Pw[wave][0];

    for (int j0 = 0; j0 < 1024; j0 += 64) {
        __syncthreads();   // all waves done reading previous Vt
        {
            const int r  = tid >> 2;
            const int dq = (tid & 3) * 4;
            uint2 vv = *(const uint2*)(V +
                (size_t)(b * 1024 + j0 + r) * 1024 + col0 + dq);
            bf16_t t4[4] __attribute__((aligned(8)));
            *(uint2*)t4 = vv;
            const int kcol = (r & 15) * 4 + (r >> 4);
            #pragma unroll
            for (int ii = 0; ii < 4; ++ii)
                Vt[(dq + ii) * 72 + kcol] = t4[ii];
        }
        bf16x8 kf[4] = {};
        if (quad < 2) {
            #pragma unroll
            for (int nt = 0; nt < 4; ++nt)
                kf[nt] = *(const bf16x8*)(K +
                    (size_t)(b * 1024 + j0 + nt * 16 + l16) * 1024 + col0 + quad * 8);
        }
        __syncthreads();   // Vt staged

        // ---- S = Q K^T (K pre-scaled), p = exp2(s), pack to P ----
        #pragma unroll
        for (int mt = 0; mt < 4; ++mt) {
            f32x4 s[4];
            #pragma unroll
            for (int nt = 0; nt < 4; ++nt) {
                f32x4 zc = {0.f, 0.f, 0.f, 0.f};
                s[nt] = __builtin_amdgcn_mfma_f32_16x16x32_bf16(qf[mt], kf[nt], zc, 0, 0, 0);
            }
            #pragma unroll
            for (int i = 0; i < 4; ++i) {
                bf16_t pk4[4] __attribute__((aligned(8)));
                #pragma unroll
                for (int nt = 0; nt < 4; ++nt)
                    pk4[nt] = (bf16_t)exp2f(s[nt][i]);
                *(uint2*)(myP + (mt * 16 + quad * 4 + i) * 72 + l16 * 4) = *(const uint2*)pk4;
            }
        }

        // ---- Z += P V ; l += P 1 ----
        #pragma unroll
        for (int kt = 0; kt < 2; ++kt) {
            bf16x8 vf = *(const bf16x8*)(&Vt[l16 * 72 + kt * 32 + quad * 8]);
            #pragma unroll
            for (int mt = 0; mt < 4; ++mt) {
                bf16x8 pf = *(const bf16x8*)(myP + (mt * 16 + l16) * 72 + kt * 32 + quad * 8);
                zacc[mt] = __builtin_amdgcn_mfma_f32_16x16x32_bf16(pf, vf, zacc[mt], 0, 0, 0);
                lacc[mt] = __builtin_amdgcn_mfma_f32_16x16x32_bf16(pf, ones, lacc[mt], 0, 0, 0);
            }
        }
    }

    #pragma unroll
    for (int mt = 0; mt < 4; ++mt) {
        #pragma unroll
        for (int i = 0; i < 4; ++i) {
            const float inv = 1.0f / lacc[mt][i];
            const int t = qbase + mt * 16 + quad * 4 + i;
            Z[((size_t)hd * 1024 + t) * 16 + l16] = (bf16_t)(zacc[mt][i] * inv);
        }
    }
}

extern "C" void kernel_launch(void* const* d_in, const int* in_sizes, int n_in,
                              void* d_out, int out_size, void* d_ws, size_t ws_size,
                              hipStream_t stream) {
    const float* x  = (const float*)d_in[0];
    const float* Wq = (const float*)d_in[1];
    const float* bq = (const float*)d_in[2];
    const float* Wk = (const float*)d_in[3];
    const float* bk = (const float*)d_in[4];
    const float* Wv = (const float*)d_in[5];
    const float* bv = (const float*)d_in[6];
    const float* Wo = (const float*)d_in[7];
    const float* bo = (const float*)d_in[8];
    float* out = (float*)d_out;

    char* ws = (char*)d_ws;
    bf16_t* x_bf = (bf16_t*)(ws);
    bf16_t* Wt   = (bf16_t*)(ws + (8u << 20));   // q|k|v|o slabs, contiguous
    bf16_t* Qb   = (bf16_t*)(ws + (16u << 20));
    bf16_t* Kb   = (bf16_t*)(ws + (24u << 20));
    bf16_t* Vb   = (bf16_t*)(ws + (32u << 20));
    bf16_t* Zb   = (bf16_t*)(ws + (40u << 20));
    bf16_t* WtO  = Wt + (size_t)3 * 1024 * 1024;

    cast_f32_bf16<<<dim3(2048), dim3(256), 0, stream>>>(x, x_bf, 524288);
    transpose_cast<<<dim3(32, 32, 4), dim3(256), 0, stream>>>(Wq, Wk, Wv, Wo, Wt);

    // fused QKV: Bt = [3072][1024] (Wq|Wk|Wv)
    gemm_glds<true><<<dim3(24, 32), dim3(256), 0, stream>>>(
        x_bf, Wt, bq, bk, bv, Qb, Kb, Vb, nullptr);

    attn_kernel<<<dim3(1024), dim3(256), 0, stream>>>(Qb, Kb, Vb, Zb);

    gemm_glds<false><<<dim3(8, 32), dim3(256), 0, stream>>>(
        Zb, WtO, bo, nullptr, nullptr, nullptr, nullptr, nullptr, out);
}